// Round 1
// baseline (3691.486 us; speedup 1.0000x reference)
//
#include <hip/hip_runtime.h>

constexpr int NB = 16, NN = 2048, NM = 2048;
constexpr float LOG2E = 1.4426950408889634f;

// ws layout (float offsets)
constexpr size_t W_SATL  = 0;                      // [NB*NN]
constexpr size_t W_SATR  = 32768;                  // [NB*NM]
constexpr size_t W_ROWA  = 65536;                  // float4[NB*NN] {x'0,x'1,x'2, rowshift}
constexpr size_t W_ROWB  = 65536 + 4*32768;        // float4[NB*NN] {x0,x1,x2, rs2}
constexpr size_t W_SPART = W_ROWB + 4*32768;       // [NB][32][NN] row-sum partials per col-tile
constexpr size_t W_LOSS  = W_SPART + (size_t)NB*32*NN;  // 1 float

__global__ __launch_bounds__(256) void k_init(float* ws) {
  int i = blockIdx.x*256 + threadIdx.x;
  if (i < NB*NM) ws[W_SATR + i] = 1.0f;
  if (i == 0) ws[W_LOSS] = 0.0f;
}

// Row kernel: satl update (from prev level's s partials), then online softmax
// over m for each row: produces rowshift/rs2 for the column kernel.
__global__ __launch_bounds__(256) void k_rows(const float* __restrict__ px,
                                              const float* __restrict__ py,
                                              float* __restrict__ ws,
                                              float lvl2, int first) {
  __shared__ float4 cpk[NM];   // {y0,y1,y2, c_m}
  const int b  = blockIdx.x >> 5;      // 32 row-blocks per batch
  const int rb = blockIdx.x & 31;
  const int tid = threadIdx.x;

  const float* satr = ws + W_SATR + (size_t)b*NM;
  #pragma unroll
  for (int k = 0; k < 8; ++k) {
    int col = tid*8 + k;
    float y0 = py[((size_t)b*NM + col)*3 + 0];
    float y1 = py[((size_t)b*NM + col)*3 + 1];
    float y2 = py[((size_t)b*NM + col)*3 + 2];
    float yn = y0*y0 + y1*y1 + y2*y2;
    float c  = fmaf(yn, lvl2, __builtin_log2f(satr[col] + 1e-30f));
    cpk[col] = make_float4(y0, y1, y2, c);
  }
  __syncthreads();

  const int rloc = tid >> 2;           // 0..63
  const int q    = tid & 3;            // 4 threads per row
  const int row  = rb*64 + rloc;
  const size_t gn = (size_t)b*NN + row;
  float x0 = px[gn*3+0], x1 = px[gn*3+1], x2 = px[gn*3+2];
  float xn = x0*x0 + x1*x1 + x2*x2;
  float an = xn * lvl2;
  float scl = -2.0f * lvl2;
  float xs0 = scl*x0, xs1 = scl*x1, xs2 = scl*x2;

  float rmax = -3.402823466e38f, rsum = 0.0f;
  for (int c8 = 0; c8 < 64; ++c8) {
    float l[8];
    #pragma unroll
    for (int i = 0; i < 8; ++i) {
      int col = 4*(c8*8 + i) + q;      // q-interleaved: conflict-free multi-broadcast
      float4 p = cpk[col];
      l[i] = fmaf(xs0, p.x, fmaf(xs1, p.y, fmaf(xs2, p.z, p.w + an)));
    }
    float m01 = fmaxf(l[0], l[1]), m23 = fmaxf(l[2], l[3]);
    float m45 = fmaxf(l[4], l[5]), m67 = fmaxf(l[6], l[7]);
    float cm  = fmaxf(fmaxf(m01, m23), fmaxf(m45, m67));
    float nm  = fmaxf(rmax, cm);
    float cs = 0.0f;
    #pragma unroll
    for (int i = 0; i < 8; ++i) cs += __builtin_exp2f(l[i] - nm);
    rsum = fmaf(rsum, __builtin_exp2f(rmax - nm), cs);
    rmax = nm;
  }

  // gather previous level's row-sum partials (32 col-tiles, 8 per q-thread)
  float sp = 0.0f;
  if (!first) {
    const float* spart = ws + W_SPART + ((size_t)b*32)*NN;
    #pragma unroll
    for (int i = 0; i < 8; ++i) sp += spart[(size_t)(q*8 + i)*NN + row];
  }

  // combine the 4 q-threads (lanes rloc*4+q: xor 1,2 stay in-group)
  #pragma unroll
  for (int d = 1; d <= 2; d <<= 1) {
    float om  = __shfl_xor(rmax, d);
    float od  = __shfl_xor(rsum, d);
    float osp = __shfl_xor(sp,  d);
    float nm  = fmaxf(rmax, om);
    rsum = rsum*__builtin_exp2f(rmax - nm) + od*__builtin_exp2f(om - nm);
    rmax = nm;
    sp += osp;
  }

  if (q == 0) {
    float sl = first ? 1.0f : ws[W_SATL + gn];
    sl = fmaxf(sl - sp, 0.0f);         // satl = max(satl - s, 0) from prev level
    ws[W_SATL + gn] = sl;
    float rs2 = __builtin_log2f(sl / rsum) - rmax;  // log2(coef) - max  (-inf ok)
    float4* rowA = (float4*)(ws + W_ROWA);
    float4* rowB = (float4*)(ws + W_ROWB);
    rowA[gn] = make_float4(xs0, xs1, xs2, rs2 + an);
    rowB[gn] = make_float4(x0, x1, x2, rs2);
  }
}

// Column kernel: phase B (raw colsums S -> ssc, satr update), phase C
// (final weights: loss + per-tile row-sum partials). Block owns (b, 64-col tile).
__global__ __launch_bounds__(256) void k_cols(const float* __restrict__ py,
                                              float* __restrict__ ws,
                                              float lvl2) {
  __shared__ float4 rowLDS[NN];        // 32KB
  __shared__ float  sspart[4][64];
  __shared__ float4 colLDS[64];
  __shared__ float  lred[4];
  const int tid = threadIdx.x;
  const int wv = tid >> 6, lane = tid & 63;
  const int b = blockIdx.x >> 5, tile = blockIdx.x & 31;
  const int col = tile*64 + lane;
  const size_t gm = (size_t)b*NM + col;

  float y0 = py[gm*3+0], y1 = py[gm*3+1], y2 = py[gm*3+2];
  float yn = y0*y0 + y1*y1 + y2*y2;
  float sr  = ws[W_SATR + gm];
  float lsr = __builtin_log2f(sr + 1e-30f);
  float cB  = fmaf(yn, lvl2, lsr);

  const float4* gRowA = (const float4*)(ws + W_ROWA) + (size_t)b*NN;
  for (int i = tid; i < NN; i += 256) rowLDS[i] = gRowA[i];
  __syncthreads();

  // phase B: lanes=columns, waves split n. S[m] = sum_n coef*e
  const int n0 = wv * 512;
  float acc = 0.0f;
  #pragma unroll 8
  for (int n = n0; n < n0 + 512; ++n) {
    float4 r = rowLDS[n];              // broadcast
    float t = fmaf(r.x, y0, fmaf(r.y, y1, fmaf(r.z, y2, r.w + cB)));
    acc += __builtin_exp2f(t);
  }
  sspart[wv][lane] = acc;
  __syncthreads();
  float S   = sspart[0][lane] + sspart[1][lane] + sspart[2][lane] + sspart[3][lane];
  float ssc = fminf(sr / (S + 1e-9f), 1.0f);
  float cC  = lsr + __builtin_log2f(ssc);     // -inf if ssc==0 -> w==0, fine
  if (wv == 0) {
    ws[W_SATR + gm] = fmaxf(sr - S*ssc, 0.0f);   // ss2 = S*ssc, local update
    colLDS[lane] = make_float4(y0, y1, y2, cC);
  }
  __syncthreads();

  // phase C: lanes=rows, iterate own 64 columns. s[n] partial is lane-local.
  const float4* gRowB = (const float4*)(ws + W_ROWB) + (size_t)b*NN;
  float* spart = ws + W_SPART + ((size_t)b*32 + tile)*NN;
  float lossa = 0.0f;
  for (int g = 0; g < 8; ++g) {
    int n = n0 + g*64 + lane;
    float4 r = gRowB[n];               // per-lane row, coalesced
    float sacc = 0.0f;
    #pragma unroll 4
    for (int c = 0; c < 64; ++c) {
      float4 cv = colLDS[c];           // broadcast
      float d0 = r.x - cv.x, d1 = r.y - cv.y, dz = r.z - cv.z;
      float d2 = fmaf(d0, d0, fmaf(d1, d1, dz*dz));
      float t  = fmaf(d2, lvl2, r.w + cv.w);
      float w  = __builtin_exp2f(t);   // = coef * e * ssc  (all folded)
      lossa = fmaf(w, d2, lossa);
      sacc += w;
    }
    spart[n] = sacc;                   // coalesced store
  }
  #pragma unroll
  for (int d = 32; d >= 1; d >>= 1) lossa += __shfl_xor(lossa, d);
  if (lane == 0) lred[wv] = lossa;
  __syncthreads();
  if (tid == 0) atomicAdd(ws + W_LOSS, lred[0]+lred[1]+lred[2]+lred[3]);
}

__global__ void k_final(const float* __restrict__ ws, float* __restrict__ out) {
  out[0] = ws[W_LOSS] * (1.0f / (float)NB);
}

extern "C" void kernel_launch(void* const* d_in, const int* in_sizes, int n_in,
                              void* d_out, int out_size, void* d_ws, size_t ws_size,
                              hipStream_t stream) {
  const float* px = (const float*)d_in[0];
  const float* py = (const float*)d_in[1];
  float* ws  = (float*)d_ws;
  float* out = (float*)d_out;

  k_init<<<dim3((NB*NM + 255)/256), dim3(256), 0, stream>>>(ws);
  for (int lv = 0; lv < 44; ++lv) {
    float level = (lv == 43) ? 0.0f : (8.0f - 0.25f*(float)lv);
    float lvl2 = level * LOG2E;
    k_rows<<<dim3(NB*32), dim3(256), 0, stream>>>(px, py, ws, lvl2, lv == 0 ? 1 : 0);
    k_cols<<<dim3(NB*32), dim3(256), 0, stream>>>(py, ws, lvl2);
  }
  k_final<<<dim3(1), dim3(1), 0, stream>>>(ws, out);
}

// Round 5
// 2542.109 us; speedup vs baseline: 1.4521x; 1.4521x over previous
//
#include <hip/hip_runtime.h>

constexpr int NB = 16, NN = 2048, NM = 2048;
constexpr float LOG2E = 1.4426950408889634f;

#define EXP2 __builtin_amdgcn_exp2f     // raw v_exp_f32 (log2-domain)
#define LOG2 __builtin_amdgcn_logf      // raw v_log_f32 (log2)

// ws layout (float offsets)
constexpr size_t W_SATL  = 0;                      // [NB*NN]
constexpr size_t W_SATR  = 32768;                  // [NB*NM]
constexpr size_t W_ROWA  = 65536;                  // float4[NB*NN] {-2L*x, rs2+L|x|^2}
constexpr size_t W_ROWB  = 65536 + 4*32768;        // float4[NB*NN] {x, rs2}
constexpr size_t W_SPART = W_ROWB + 4*32768;       // [NB][32][NN] row-sum partials per col-tile
constexpr size_t W_LOSS  = W_SPART + (size_t)NB*32*NN;  // 1 float

__global__ __launch_bounds__(256) void k_init(float* ws) {
  int i = blockIdx.x*256 + threadIdx.x;
  if (i < NB*NM) ws[W_SATR + i] = 1.0f;
  if (i == 0) ws[W_LOSS] = 0.0f;
}

// Row kernel: satl update (from prev level's s partials) + online softmax over m.
// 512 threads = 64 rows x 8 q-threads. Grid NB*32.
__global__ __launch_bounds__(512) void k_rows(const float* __restrict__ px,
                                              const float* __restrict__ py,
                                              float* __restrict__ ws,
                                              float lvl2, int first) {
  __shared__ float4 cpk[NM];   // {y0,y1,y2, c_m = L*|y|^2 + log2(satr+eps)}
  const int b  = blockIdx.x >> 5;
  const int rb = blockIdx.x & 31;
  const int tid = threadIdx.x;

  // stage columns: 4 cols/thread, vector-load 12 floats as 3 float4
  {
    const float* satr = ws + W_SATR + (size_t)b*NM;
    const float4* pyv = (const float4*)(py + (size_t)b*NM*3);
    float4 pA = pyv[tid*3+0], pB = pyv[tid*3+1], pC = pyv[tid*3+2];
    float yy[12] = {pA.x,pA.y,pA.z,pA.w, pB.x,pB.y,pB.z,pB.w, pC.x,pC.y,pC.z,pC.w};
    #pragma unroll
    for (int k = 0; k < 4; ++k) {
      int col = tid*4 + k;
      float y0 = yy[3*k], y1 = yy[3*k+1], y2 = yy[3*k+2];
      float yn = y0*y0 + y1*y1 + y2*y2;
      float c  = fmaf(yn, lvl2, LOG2(satr[col] + 1e-30f));
      cpk[col] = make_float4(y0, y1, y2, c);
    }
  }
  __syncthreads();

  const int rloc = tid >> 3;           // 0..63
  const int q    = tid & 7;            // 8 threads per row
  const int row  = rb*64 + rloc;
  const size_t gn = (size_t)b*NN + row;
  float x0 = px[gn*3+0], x1 = px[gn*3+1], x2 = px[gn*3+2];
  float xn = x0*x0 + x1*x1 + x2*x2;
  float an = xn * lvl2;
  float scl = -2.0f * lvl2;
  float xs0 = scl*x0, xs1 = scl*x1, xs2 = scl*x2;

  float rmax = -3.402823466e38f, rsum = 0.0f;
  for (int c8 = 0; c8 < 32; ++c8) {
    float l[8];
    #pragma unroll
    for (int i = 0; i < 8; ++i) {
      int col = (c8*8 + i)*8 + q;      // q-interleaved: 8x16B multicast, conflict-free
      float4 p = cpk[col];
      l[i] = fmaf(xs0, p.x, fmaf(xs1, p.y, fmaf(xs2, p.z, p.w + an)));
    }
    float m01 = fmaxf(l[0], l[1]), m23 = fmaxf(l[2], l[3]);
    float m45 = fmaxf(l[4], l[5]), m67 = fmaxf(l[6], l[7]);
    float cm  = fmaxf(fmaxf(m01, m23), fmaxf(m45, m67));
    float nm  = fmaxf(rmax, cm);
    float cs = 0.0f;
    #pragma unroll
    for (int i = 0; i < 8; ++i) cs += EXP2(l[i] - nm);
    rsum = fmaf(rsum, EXP2(rmax - nm), cs);
    rmax = nm;
  }

  // gather previous level's row-sum partials (32 col-tiles, 4 per q-thread)
  float sp = 0.0f;
  if (!first) {
    const float* spart = ws + W_SPART + ((size_t)b*32)*NN;
    #pragma unroll
    for (int i = 0; i < 4; ++i) sp += spart[(size_t)(q*4 + i)*NN + row];
  }

  // combine the 8 q-threads (lanes rloc*8+q: xor 1,2,4 stay in-group)
  #pragma unroll
  for (int d = 1; d <= 4; d <<= 1) {
    float om  = __shfl_xor(rmax, d);
    float od  = __shfl_xor(rsum, d);
    float osp = __shfl_xor(sp,  d);
    float nm  = fmaxf(rmax, om);
    rsum = rsum*EXP2(rmax - nm) + od*EXP2(om - nm);
    rmax = nm;
    sp += osp;
  }

  if (q == 0) {
    float sl = first ? 1.0f : ws[W_SATL + gn];
    sl = fmaxf(sl - sp, 0.0f);
    ws[W_SATL + gn] = sl;
    float rs2 = LOG2(sl / rsum) - rmax;     // -inf ok (v_exp of -inf -> 0)
    float4* rowA = (float4*)(ws + W_ROWA);
    float4* rowB = (float4*)(ws + W_ROWB);
    rowA[gn] = make_float4(xs0, xs1, xs2, rs2 + an);
    rowB[gn] = make_float4(x0, x1, x2, rs2);
  }
}

// Column kernel: 512 threads, block owns (b, 64-col tile). Grid NB*32.
// Phase B: colsums S -> ssc, satr update. Phase C: loss + row-sum partials.
__global__ __launch_bounds__(512) void k_cols(const float* __restrict__ py,
                                              float* __restrict__ ws,
                                              float lvl2) {
  __shared__ float4 rowLDS[NN];        // 32KB
  __shared__ float  sspart[8][64];
  __shared__ float4 colLDS[64];
  __shared__ float  lred[8];
  const int tid = threadIdx.x;
  const int wv = tid >> 6, lane = tid & 63;
  const int b = blockIdx.x >> 5, tile = blockIdx.x & 31;
  const int col = tile*64 + lane;
  const size_t gm = (size_t)b*NM + col;

  float y0 = py[gm*3+0], y1 = py[gm*3+1], y2 = py[gm*3+2];
  float yn = y0*y0 + y1*y1 + y2*y2;
  float sr  = ws[W_SATR + gm];
  float lsr = LOG2(sr + 1e-30f);
  float cB  = fmaf(yn, lvl2, lsr);

  const float4* gRowA = (const float4*)(ws + W_ROWA) + (size_t)b*NN;
  for (int i = tid; i < NN; i += 512) rowLDS[i] = gRowA[i];
  __syncthreads();

  // phase B: lanes=columns, 8 waves split n (256 each)
  const int n0 = wv * 256;
  float acc = 0.0f;
  #pragma unroll 8
  for (int n = n0; n < n0 + 256; ++n) {
    float4 r = rowLDS[n];              // broadcast
    float t = fmaf(r.x, y0, fmaf(r.y, y1, fmaf(r.z, y2, r.w + cB)));
    acc += EXP2(t);
  }
  sspart[wv][lane] = acc;
  __syncthreads();
  if (wv == 0) {
    float S = 0.0f;
    #pragma unroll
    for (int w = 0; w < 8; ++w) S += sspart[w][lane];
    float ssc = fminf(sr / (S + 1e-9f), 1.0f);
    float cC  = lsr + LOG2(ssc);       // -inf if ssc==0 -> w==0
    ws[W_SATR + gm] = fmaxf(sr - S*ssc, 0.0f);
    colLDS[lane] = make_float4(y0, y1, y2, cC);
  }
  __syncthreads();

  // phase C: lanes=rows; 4 rows/thread held in registers; cols outer.
  const float4* gRowB = (const float4*)(ws + W_ROWB) + (size_t)b*NN;
  float* spart = ws + W_SPART + ((size_t)b*32 + tile)*NN;
  float4 r0 = gRowB[0*512 + tid];
  float4 r1 = gRowB[1*512 + tid];
  float4 r2 = gRowB[2*512 + tid];
  float4 r3 = gRowB[3*512 + tid];
  float s0 = 0.f, s1 = 0.f, s2 = 0.f, s3 = 0.f;
  float lossa = 0.0f;
  #pragma unroll 4
  for (int c = 0; c < 64; ++c) {
    float4 cv = colLDS[c];             // broadcast, once per 4 rows
    {
      float d0 = r0.x-cv.x, d1 = r0.y-cv.y, dz = r0.z-cv.z;
      float d2 = fmaf(d0,d0, fmaf(d1,d1, dz*dz));
      float w  = EXP2(fmaf(d2, lvl2, r0.w + cv.w));
      lossa = fmaf(w, d2, lossa); s0 += w;
    }
    {
      float d0 = r1.x-cv.x, d1 = r1.y-cv.y, dz = r1.z-cv.z;
      float d2 = fmaf(d0,d0, fmaf(d1,d1, dz*dz));
      float w  = EXP2(fmaf(d2, lvl2, r1.w + cv.w));
      lossa = fmaf(w, d2, lossa); s1 += w;
    }
    {
      float d0 = r2.x-cv.x, d1 = r2.y-cv.y, dz = r2.z-cv.z;
      float d2 = fmaf(d0,d0, fmaf(d1,d1, dz*dz));
      float w  = EXP2(fmaf(d2, lvl2, r2.w + cv.w));
      lossa = fmaf(w, d2, lossa); s2 += w;
    }
    {
      float d0 = r3.x-cv.x, d1 = r3.y-cv.y, dz = r3.z-cv.z;
      float d2 = fmaf(d0,d0, fmaf(d1,d1, dz*dz));
      float w  = EXP2(fmaf(d2, lvl2, r3.w + cv.w));
      lossa = fmaf(w, d2, lossa); s3 += w;
    }
  }
  spart[0*512 + tid] = s0;
  spart[1*512 + tid] = s1;
  spart[2*512 + tid] = s2;
  spart[3*512 + tid] = s3;

  #pragma unroll
  for (int d = 32; d >= 1; d >>= 1) lossa += __shfl_xor(lossa, d);
  if (lane == 0) lred[wv] = lossa;
  __syncthreads();
  if (tid == 0) {
    float t = 0.f;
    #pragma unroll
    for (int w = 0; w < 8; ++w) t += lred[w];
    atomicAdd(ws + W_LOSS, t);
  }
}

__global__ void k_final(const float* __restrict__ ws, float* __restrict__ out) {
  out[0] = ws[W_LOSS] * (1.0f / (float)NB);
}

extern "C" void kernel_launch(void* const* d_in, const int* in_sizes, int n_in,
                              void* d_out, int out_size, void* d_ws, size_t ws_size,
                              hipStream_t stream) {
  const float* px = (const float*)d_in[0];
  const float* py = (const float*)d_in[1];
  float* ws  = (float*)d_ws;
  float* out = (float*)d_out;

  k_init<<<dim3((NB*NM + 255)/256), dim3(256), 0, stream>>>(ws);
  for (int lv = 0; lv < 44; ++lv) {
    float level = (lv == 43) ? 0.0f : (8.0f - 0.25f*(float)lv);
    float lvl2 = level * LOG2E;
    k_rows<<<dim3(NB*32), dim3(512), 0, stream>>>(px, py, ws, lvl2, lv == 0 ? 1 : 0);
    k_cols<<<dim3(NB*32), dim3(512), 0, stream>>>(py, ws, lvl2);
  }
  k_final<<<dim3(1), dim3(1), 0, stream>>>(ws, out);
}

// Round 7
// 2156.605 us; speedup vs baseline: 1.7117x; 1.1788x over previous
//
#include <hip/hip_runtime.h>

constexpr int NB = 16, NN = 2048, NM = 2048;
constexpr float LOG2E = 1.4426950408889634f;

#define EXP2 __builtin_amdgcn_exp2f     // raw v_exp_f32 (log2-domain)
#define LOG2 __builtin_amdgcn_logf      // raw v_log_f32 (log2)

typedef float f32x2 __attribute__((ext_vector_type(2)));
typedef float f32x4 __attribute__((ext_vector_type(4)));

static __device__ __forceinline__ f32x2 pk_fma(f32x2 a, f32x2 b, f32x2 c) {
  return __builtin_elementwise_fma(a, b, c);
}
static __device__ __forceinline__ f32x2 pk_max(f32x2 a, f32x2 b) {
  return __builtin_elementwise_max(a, b);
}

// ws layout (float offsets). Row arrays are PAIR-INTERLEAVED:
// pair j (rows 2j,2j+1) = 8 floats: {x0,x1, y0,y1, z0,z1, w0,w1}
constexpr size_t W_SATL  = 0;                      // [NB*NN]
constexpr size_t W_SATR  = 32768;                  // [NB*NM]
constexpr size_t W_ROWA  = 65536;                  // pair-f32x4[NB*NN] {-2L*x pairs, rs2+L|x|^2 pairs}
constexpr size_t W_ROWB  = 65536 + 4*32768;        // pair-f32x4[NB*NN] {x pairs, rs2 pairs}
constexpr size_t W_SPART = W_ROWB + 4*32768;       // [NB][32][NN] row-sum partials per col-tile
constexpr size_t W_LOSS  = W_SPART + (size_t)NB*32*NN;  // 1 float

__global__ __launch_bounds__(256) void k_init(float* ws) {
  int i = blockIdx.x*256 + threadIdx.x;
  if (i < NB*NM) ws[W_SATR + i] = 1.0f;
  if (i == 0) ws[W_LOSS] = 0.0f;
}

// Row kernel: satl update (from prev level's s partials) + online softmax over m.
// 512 threads = 64 rows x 8 q-threads. Grid NB*32.
__global__ __launch_bounds__(512) void k_rows(const float* __restrict__ px,
                                              const float* __restrict__ py,
                                              float* __restrict__ ws,
                                              float lvl2, int first) {
  __shared__ f32x4 cpk[NM];   // pair-interleaved: pair p -> [2p]={y0 pair,y1 pair},[2p+1]={y2 pair,cm pair}
  const int b  = blockIdx.x >> 5;
  const int rb = blockIdx.x & 31;
  const int tid = threadIdx.x;

  // stage columns: 4 cols/thread (= pairs 2t,2t+1), vector-load 12 floats as 3 float4
  {
    const float* satr = ws + W_SATR + (size_t)b*NM;
    const float4* pyv = (const float4*)(py + (size_t)b*NM*3);
    float4 pA = pyv[tid*3+0], pB = pyv[tid*3+1], pC = pyv[tid*3+2];
    float yy[12] = {pA.x,pA.y,pA.z,pA.w, pB.x,pB.y,pB.z,pB.w, pC.x,pC.y,pC.z,pC.w};
    float cm[4];
    #pragma unroll
    for (int k = 0; k < 4; ++k) {
      int col = tid*4 + k;
      float y0 = yy[3*k], y1 = yy[3*k+1], y2 = yy[3*k+2];
      float yn = y0*y0 + y1*y1 + y2*y2;
      cm[k] = fmaf(yn, lvl2, LOG2(satr[col] + 1e-30f));
    }
    #pragma unroll
    for (int k2 = 0; k2 < 2; ++k2) {   // pair 2t+k2 = cols 4t+2k2, 4t+2k2+1
      int ka = 2*k2, kb = 2*k2+1;
      f32x4 lo = {yy[3*ka], yy[3*kb], yy[3*ka+1], yy[3*kb+1]};
      f32x4 hi = {yy[3*ka+2], yy[3*kb+2], cm[ka], cm[kb]};
      cpk[(2*tid + k2)*2 + 0] = lo;
      cpk[(2*tid + k2)*2 + 1] = hi;
    }
  }
  __syncthreads();

  const int rloc = tid >> 3;           // 0..63
  const int q    = tid & 7;            // 8 threads per row
  const int row  = rb*64 + rloc;
  const size_t gn = (size_t)b*NN + row;
  float x0 = px[gn*3+0], x1 = px[gn*3+1], x2 = px[gn*3+2];
  float xn = x0*x0 + x1*x1 + x2*x2;
  float an = xn * lvl2;
  float scl = -2.0f * lvl2;
  float xs0 = scl*x0, xs1 = scl*x1, xs2 = scl*x2;
  f32x2 xs0p = {xs0,xs0}, xs1p = {xs1,xs1}, xs2p = {xs2,xs2}, anp = {an,an};

  float rmax = -3.402823466e38f, rsum = 0.0f;
  for (int c8 = 0; c8 < 32; ++c8) {
    f32x2 lp[4];
    #pragma unroll
    for (int i = 0; i < 4; ++i) {
      int pj = (c8*4 + i)*8 + q;       // pair index, q-interleaved multicast
      f32x4 a  = cpk[2*pj];
      f32x4 b2 = cpk[2*pj+1];
      lp[i] = pk_fma(xs0p, a.xy, pk_fma(xs1p, a.zw, pk_fma(xs2p, b2.xy, b2.zw + anp)));
    }
    f32x2 mp = pk_max(pk_max(lp[0], lp[1]), pk_max(lp[2], lp[3]));
    float cm  = fmaxf(mp.x, mp.y);
    float nm  = fmaxf(rmax, cm);
    f32x2 nms = {nm, nm};
    f32x2 e0 = lp[0] - nms, e1 = lp[1] - nms, e2 = lp[2] - nms, e3 = lp[3] - nms;
    float cs = ((EXP2(e0.x) + EXP2(e0.y)) + (EXP2(e1.x) + EXP2(e1.y)))
             + ((EXP2(e2.x) + EXP2(e2.y)) + (EXP2(e3.x) + EXP2(e3.y)));
    rsum = fmaf(rsum, EXP2(rmax - nm), cs);
    rmax = nm;
  }

  // gather previous level's row-sum partials (32 col-tiles, 4 per q-thread)
  float sp = 0.0f;
  if (!first) {
    const float* spart = ws + W_SPART + ((size_t)b*32)*NN;
    #pragma unroll
    for (int i = 0; i < 4; ++i) sp += spart[(size_t)(q*4 + i)*NN + row];
  }

  // combine the 8 q-threads (lanes rloc*8+q: xor 1,2,4 stay in-group)
  #pragma unroll
  for (int d = 1; d <= 4; d <<= 1) {
    float om  = __shfl_xor(rmax, d);
    float od  = __shfl_xor(rsum, d);
    float osp = __shfl_xor(sp,  d);
    float nm  = fmaxf(rmax, om);
    rsum = rsum*EXP2(rmax - nm) + od*EXP2(om - nm);
    rmax = nm;
    sp += osp;
  }

  if (q == 0) {
    float sl = first ? 1.0f : ws[W_SATL + gn];
    sl = fmaxf(sl - sp, 0.0f);
    ws[W_SATL + gn] = sl;
    float rs2 = LOG2(sl / rsum) - rmax;     // -inf ok (v_exp of -inf -> 0)
    // pair-interleaved writes: row -> pair row>>1, slot row&1
    size_t pbase = (size_t)b*NN*4 + (size_t)(row >> 1)*8 + (row & 1);
    float* A  = ws + W_ROWA + pbase;
    float* Bq = ws + W_ROWB + pbase;
    A[0] = xs0; A[2] = xs1; A[4] = xs2; A[6] = rs2 + an;
    Bq[0] = x0; Bq[2] = x1; Bq[4] = x2; Bq[6] = rs2;
  }
}

// Column kernel: 512 threads, block owns (b, 64-col tile). Grid NB*32.
// Phase B: colsums S -> ssc, satr update. Phase C: loss + row-sum partials.
__global__ __launch_bounds__(512) void k_cols(const float* __restrict__ py,
                                              float* __restrict__ ws,
                                              float lvl2) {
  __shared__ f32x4 rowLDS[NN];         // 32KB, pair-interleaved rowA
  __shared__ float  sspart[8][64];
  __shared__ float4 colLDS[64];
  __shared__ float  lred[8];
  const int tid = threadIdx.x;
  const int wv = tid >> 6, lane = tid & 63;
  const int b = blockIdx.x >> 5, tile = blockIdx.x & 31;
  const int col = tile*64 + lane;
  const size_t gm = (size_t)b*NM + col;

  float y0 = py[gm*3+0], y1 = py[gm*3+1], y2 = py[gm*3+2];
  float yn = y0*y0 + y1*y1 + y2*y2;
  float sr  = ws[W_SATR + gm];
  float lsr = LOG2(sr + 1e-30f);
  float cB  = fmaf(yn, lvl2, lsr);

  const f32x4* gRowA = (const f32x4*)(ws + W_ROWA) + (size_t)b*NN;
  for (int i = tid; i < NN; i += 512) rowLDS[i] = gRowA[i];
  __syncthreads();

  // phase B: lanes=columns, 8 waves split n (128 pairs each), packed
  const int p0 = wv * 128;
  f32x2 y0p = {y0,y0}, y1p = {y1,y1}, y2p = {y2,y2}, cBp = {cB,cB};
  f32x2 accp = {0.f, 0.f};
  #pragma unroll 8
  for (int j = p0; j < p0 + 128; ++j) {
    f32x4 a  = rowLDS[2*j];            // {x pair, y pair} broadcast
    f32x4 b2 = rowLDS[2*j+1];          // {z pair, w pair}
    f32x2 t = pk_fma(a.xy, y0p, pk_fma(a.zw, y1p, pk_fma(b2.xy, y2p, b2.zw + cBp)));
    accp.x += EXP2(t.x);
    accp.y += EXP2(t.y);
  }
  sspart[wv][lane] = accp.x + accp.y;
  __syncthreads();
  if (wv == 0) {
    float S = 0.0f;
    #pragma unroll
    for (int w = 0; w < 8; ++w) S += sspart[w][lane];
    float ssc = fminf(sr / (S + 1e-9f), 1.0f);
    float cC  = lsr + LOG2(ssc);       // -inf if ssc==0 -> w==0
    ws[W_SATR + gm] = fmaxf(sr - S*ssc, 0.0f);
    colLDS[lane] = make_float4(y0, y1, y2, cC);
  }
  __syncthreads();

  // phase C: 2 row-pairs per thread (rows 2t,2t+1 and 1024+2t,1024+2t+1), packed
  const f32x4* gRowB = (const f32x4*)(ws + W_ROWB) + (size_t)b*NN;
  float* spart = ws + W_SPART + ((size_t)b*32 + tile)*NN;
  f32x4 p0a = gRowB[2*tid],        p0b = gRowB[2*tid+1];
  f32x4 p1a = gRowB[2*(tid+512)],  p1b = gRowB[2*(tid+512)+1];
  f32x2 sA = {0,0}, sB = {0,0}, lossp = {0,0};
  f32x2 L2p = {lvl2, lvl2};
  #pragma unroll 4
  for (int c = 0; c < 64; ++c) {
    float4 cv = colLDS[c];             // broadcast
    f32x2 cx = {cv.x,cv.x}, cy = {cv.y,cv.y}, cz = {cv.z,cv.z}, cw = {cv.w,cv.w};
    {
      f32x2 d0 = p0a.xy - cx, d1 = p0a.zw - cy, dz = p0b.xy - cz;
      f32x2 d2 = pk_fma(d0, d0, pk_fma(d1, d1, dz*dz));
      f32x2 tt = pk_fma(d2, L2p, p0b.zw + cw);
      f32x2 w; w.x = EXP2(tt.x); w.y = EXP2(tt.y);
      lossp = pk_fma(w, d2, lossp); sA += w;
    }
    {
      f32x2 d0 = p1a.xy - cx, d1 = p1a.zw - cy, dz = p1b.xy - cz;
      f32x2 d2 = pk_fma(d0, d0, pk_fma(d1, d1, dz*dz));
      f32x2 tt = pk_fma(d2, L2p, p1b.zw + cw);
      f32x2 w; w.x = EXP2(tt.x); w.y = EXP2(tt.y);
      lossp = pk_fma(w, d2, lossp); sB += w;
    }
  }
  // rows 2t,2t+1 are consecutive floats in spart -> float2 store at index t
  ((float2*)spart)[tid]       = make_float2(sA.x, sA.y);
  ((float2*)spart)[tid + 512] = make_float2(sB.x, sB.y);

  float lossa = lossp.x + lossp.y;
  #pragma unroll
  for (int d = 32; d >= 1; d >>= 1) lossa += __shfl_xor(lossa, d);
  if (lane == 0) lred[wv] = lossa;
  __syncthreads();
  if (tid == 0) {
    float t = 0.f;
    #pragma unroll
    for (int w = 0; w < 8; ++w) t += lred[w];
    atomicAdd(ws + W_LOSS, t);
  }
}

__global__ void k_final(const float* __restrict__ ws, float* __restrict__ out) {
  out[0] = ws[W_LOSS] * (1.0f / (float)NB);
}

extern "C" void kernel_launch(void* const* d_in, const int* in_sizes, int n_in,
                              void* d_out, int out_size, void* d_ws, size_t ws_size,
                              hipStream_t stream) {
  const float* px = (const float*)d_in[0];
  const float* py = (const float*)d_in[1];
  float* ws  = (float*)d_ws;
  float* out = (float*)d_out;

  k_init<<<dim3((NB*NM + 255)/256), dim3(256), 0, stream>>>(ws);
  for (int lv = 0; lv < 44; ++lv) {
    float level = (lv == 43) ? 0.0f : (8.0f - 0.25f*(float)lv);
    float lvl2 = level * LOG2E;
    k_rows<<<dim3(NB*32), dim3(512), 0, stream>>>(px, py, ws, lvl2, lv == 0 ? 1 : 0);
    k_cols<<<dim3(NB*32), dim3(512), 0, stream>>>(py, ws, lvl2);
  }
  k_final<<<dim3(1), dim3(1), 0, stream>>>(ws, out);
}